// Round 1
// baseline (28.878 us; speedup 1.0000x reference)
//
#include <hip/hip_runtime.h>
#include <math.h>

#define PRE_LEN 64
#define BATCH   1024
#define NNB     256
#define MASS_F  60.0f

// One block per batch b. 256 threads = 4 waves.
// tid = q*64 + t : t = timestep (lane), q = neighbour-chunk (wave index).
// Wave q iterates neighbours n = q*64 .. q*64+63 — same LDS address across
// all 64 lanes each iteration -> LDS broadcast, no bank conflicts.
__global__ __launch_bounds__(256) void field_loss_kernel(
    const float* __restrict__ output,   // [PRE_LEN][BATCH][2]
    const float* __restrict__ target,   // [PRE_LEN][BATCH][2]
    const float* __restrict__ nbr,      // [BATCH][NNB][5]
    float* __restrict__ out)            // [1]
{
    __shared__ float s_nx[NNB], s_ny[NNB], s_ca[NNB], s_sa[NNB];
    __shared__ float s_ex[4][64], s_ey[4][64];

    const int b   = blockIdx.x;
    const int tid = threadIdx.x;

    // Stage neighbour data; hoist sincos(ang) out of the t-loop (done once
    // per (b,n) instead of once per (b,t,n): 262K sincos vs 16.8M).
    {
        const float* p = nbr + ((size_t)b * NNB + tid) * 5;
        float nx  = p[0];
        float ny  = p[1];
        float ang = p[4];
        float s, c;
        __sincosf(ang, &s, &c);   // |ang| small (N(0,1)); HW sin/cos fine at 2% tol
        s_nx[tid] = nx;
        s_ny[tid] = ny;
        s_ca[tid] = c;
        s_sa[tid] = s;
    }
    __syncthreads();

    const int t = tid & 63;
    const int q = tid >> 6;

    const size_t o_idx = (size_t)t * (BATCH * 2) + (size_t)b * 2;
    const float px = output[o_idx + 0];
    const float py = output[o_idx + 1];

    float ex = 0.0f, ey = 0.0f;
    const int n0 = q * 64;
#pragma unroll 8
    for (int i = 0; i < 64; ++i) {
        const int n = n0 + i;
        const float nx = s_nx[n], ny = s_ny[n];
        const float ca = s_ca[n], sa = s_sa[n];
        const float dx = px - nx;
        const float dy = py - ny;
        // rotate into the neighbour frame
        const float x_ = ca * dx + sa * dy;
        const float y_ = ca * dy - sa * dx;
        const float x2 = x_ * x_;
        const float y2 = y_ * y_;
        const float den = x2 * x2 * x2 + y2 * y2 * y2 + 6.0f;  // x^6 + y^6 + 6
        const float e   = MASS_F * __builtin_amdgcn_rcpf(den);
        // cos(atan2(-dy,-dx)) = -dx/r ; sin(...) = -dy/r
        const float r2   = dx * dx + dy * dy;
        const float rinv = __builtin_amdgcn_rsqf(r2);
        const float s    = e * rinv;
        ex -= s * dx;
        ey -= s * dy;
    }

    s_ex[q][t] = ex;
    s_ey[q][t] = ey;
    __syncthreads();

    if (q == 0) {
        const float tex = s_ex[0][t] + s_ex[1][t] + s_ex[2][t] + s_ex[3][t];
        const float tey = s_ey[0][t] + s_ey[1][t] + s_ey[2][t] + s_ey[3][t];
        const float en  = sqrtf(tex * tex + tey * tey);

        // fold loss1 (MSE) into the same reduction
        const float tx = target[o_idx + 0];
        const float ty = target[o_idx + 1];
        const float ddx = px - tx, ddy = py - ty;

        float val = en * (1.0f / (PRE_LEN * BATCH))
                  + (ddx * ddx + ddy * ddy) * (1.0f / (PRE_LEN * BATCH * 2));

        // 64-lane wave reduction
        #pragma unroll
        for (int off = 32; off > 0; off >>= 1)
            val += __shfl_down(val, off, 64);

        if (t == 0)
            atomicAdd(out, val);   // one atomic per block (1024 total)
    }
}

extern "C" void kernel_launch(void* const* d_in, const int* in_sizes, int n_in,
                              void* d_out, int out_size, void* d_ws, size_t ws_size,
                              hipStream_t stream) {
    const float* output = (const float*)d_in[0];
    const float* target = (const float*)d_in[1];
    const float* nbr    = (const float*)d_in[2];
    float* out = (float*)d_out;

    // d_out is poisoned once and never re-poisoned between replays; we
    // accumulate via atomics, so zero it every call (graph-capture safe).
    hipMemsetAsync(out, 0, sizeof(float), stream);
    field_loss_kernel<<<dim3(BATCH), dim3(256), 0, stream>>>(output, target, nbr, out);
}

// Round 2
// 27.619 us; speedup vs baseline: 1.0456x; 1.0456x over previous
//
#include <hip/hip_runtime.h>
#include <math.h>

#define PRE_LEN 64
#define BATCH   1024
#define NNB     256

// One block per batch b. 512 threads = 8 waves.
// tid = q*64 + t : t = timestep (lane), q = neighbour-chunk (wave index 0..7).
// Each wave iterates 32 neighbours with a uniform LDS address per iteration
// -> ds_read_b128 broadcast, zero bank conflicts.
// __launch_bounds__(512, 8): demand <=64 VGPR so 4 blocks/CU = 32 waves/CU.
__global__ __launch_bounds__(512, 8) void field_loss_kernel(
    const float* __restrict__ output,   // [PRE_LEN][BATCH][2]
    const float* __restrict__ target,   // [PRE_LEN][BATCH][2]
    const float* __restrict__ nbr,      // [BATCH][NNB][5]
    float* __restrict__ out)            // [1]
{
    __shared__ float4 s_nb[NNB];            // {nx, ny, cos(ang), sin(ang)}
    __shared__ float  s_ex[8][64], s_ey[8][64];

    const int b   = blockIdx.x;
    const int tid = threadIdx.x;

    // Stage neighbour data once per block; sincos hoisted out of the t-loop.
    if (tid < NNB) {
        const float* p = nbr + ((size_t)b * NNB + tid) * 5;
        const float nx  = p[0];
        const float ny  = p[1];
        const float ang = p[4];
        float s, c;
        __sincosf(ang, &s, &c);
        s_nb[tid] = make_float4(nx, ny, c, s);
    }
    __syncthreads();

    const int t = tid & 63;
    const int q = tid >> 6;   // 0..7

    const size_t o_idx = (size_t)t * (BATCH * 2) + (size_t)b * 2;
    const float px = output[o_idx + 0];
    const float py = output[o_idx + 1];

    float ex = 0.0f, ey = 0.0f;
    const int n0 = q * 32;
#pragma unroll 4
    for (int i = 0; i < 32; ++i) {
        const float4 nb = s_nb[n0 + i];       // one ds_read_b128, broadcast
        const float dx = px - nb.x;
        const float dy = py - nb.y;
        // rotate into neighbour frame
        const float x  = nb.z * dx + nb.w * dy;
        const float y  = nb.z * dy - nb.w * dx;
        const float x2 = x * x;
        const float y2 = y * y;
        const float den = x2 * x2 * x2 + y2 * y2 * y2 + 6.0f;  // >= 6
        const float r2  = dx * dx + dy * dy;
        // energy_i / r = 60 / (den * sqrt(r2)) = 60 * rsq(den^2 * r2)
        const float m = den * den * r2;
        const float s = 60.0f * __builtin_amdgcn_rsqf(m);
        // cos(atan2(-dy,-dx)) = -dx/r ; sin = -dy/r
        ex -= s * dx;
        ey -= s * dy;
    }

    s_ex[q][t] = ex;
    s_ey[q][t] = ey;
    __syncthreads();

    if (q == 0) {
        float tex = 0.0f, tey = 0.0f;
        #pragma unroll
        for (int k = 0; k < 8; ++k) { tex += s_ex[k][t]; tey += s_ey[k][t]; }
        const float en = sqrtf(tex * tex + tey * tey);

        // fold loss1 (MSE) into the same reduction
        const float tx = target[o_idx + 0];
        const float ty = target[o_idx + 1];
        const float ddx = px - tx, ddy = py - ty;

        float val = en * (1.0f / (PRE_LEN * BATCH))
                  + (ddx * ddx + ddy * ddy) * (1.0f / (PRE_LEN * BATCH * 2));

        // 64-lane wave reduction
        #pragma unroll
        for (int off = 32; off > 0; off >>= 1)
            val += __shfl_down(val, off, 64);

        if (t == 0)
            atomicAdd(out, val);   // one atomic per block (1024 total)
    }
}

extern "C" void kernel_launch(void* const* d_in, const int* in_sizes, int n_in,
                              void* d_out, int out_size, void* d_ws, size_t ws_size,
                              hipStream_t stream) {
    const float* output = (const float*)d_in[0];
    const float* target = (const float*)d_in[1];
    const float* nbr    = (const float*)d_in[2];
    float* out = (float*)d_out;

    // We accumulate into d_out with atomics and the harness does not
    // re-poison between replays -> zero it every call (graph-capture safe).
    hipMemsetAsync(out, 0, sizeof(float), stream);
    field_loss_kernel<<<dim3(BATCH), dim3(512), 0, stream>>>(output, target, nbr, out);
}

// Round 3
// 20.101 us; speedup vs baseline: 1.4366x; 1.3740x over previous
//
#include <hip/hip_runtime.h>
#include <math.h>

#define PRE_LEN 64
#define BATCH   1024
#define NNB     256

// Stage 1: one block per batch b. 512 threads = 8 waves.
// tid = q*64 + t : t = timestep (lane), q = neighbour-chunk (wave 0..7).
// Uniform LDS address per iteration -> ds_read_b128 broadcast, no conflicts.
// Per-block partial goes to ws[b] as a plain store (NO same-address atomic:
// 1024 contended atomicAdds to one cacheline across 8 XCDs was a ~20us tail).
__global__ __launch_bounds__(512, 8) void field_loss_kernel(
    const float* __restrict__ output,   // [PRE_LEN][BATCH][2]
    const float* __restrict__ target,   // [PRE_LEN][BATCH][2]
    const float* __restrict__ nbr,      // [BATCH][NNB][5]
    float* __restrict__ ws)             // [BATCH] partials
{
    __shared__ float4 s_nb[NNB];            // {nx, ny, cos(ang), sin(ang)}
    __shared__ float  s_ex[8][64], s_ey[8][64];

    const int b   = blockIdx.x;
    const int tid = threadIdx.x;

    if (tid < NNB) {
        const float* p = nbr + ((size_t)b * NNB + tid) * 5;
        const float nx  = p[0];
        const float ny  = p[1];
        const float ang = p[4];
        float s, c;
        __sincosf(ang, &s, &c);
        s_nb[tid] = make_float4(nx, ny, c, s);
    }
    __syncthreads();

    const int t = tid & 63;
    const int q = tid >> 6;   // 0..7

    const size_t o_idx = (size_t)t * (BATCH * 2) + (size_t)b * 2;
    const float px = output[o_idx + 0];
    const float py = output[o_idx + 1];

    float ex = 0.0f, ey = 0.0f;
    const int n0 = q * 32;
#pragma unroll 4
    for (int i = 0; i < 32; ++i) {
        const float4 nb = s_nb[n0 + i];       // one ds_read_b128, broadcast
        const float dx = px - nb.x;
        const float dy = py - nb.y;
        const float x  = nb.z * dx + nb.w * dy;
        const float y  = nb.z * dy - nb.w * dx;
        const float x2 = x * x;
        const float y2 = y * y;
        const float den = x2 * x2 * x2 + y2 * y2 * y2 + 6.0f;  // >= 6
        const float r2  = dx * dx + dy * dy;
        // energy_i / r = 60 / (den * sqrt(r2)) = 60 * rsq(den^2 * r2)
        const float m = den * den * r2;
        const float s = 60.0f * __builtin_amdgcn_rsqf(m);
        ex -= s * dx;                         // cos(atan2(-dy,-dx)) = -dx/r
        ey -= s * dy;
    }

    s_ex[q][t] = ex;
    s_ey[q][t] = ey;
    __syncthreads();

    if (q == 0) {
        float tex = 0.0f, tey = 0.0f;
        #pragma unroll
        for (int k = 0; k < 8; ++k) { tex += s_ex[k][t]; tey += s_ey[k][t]; }
        const float en = sqrtf(tex * tex + tey * tey);

        // fold loss1 (MSE) into the same per-(b,t) value
        const float tx = target[o_idx + 0];
        const float ty = target[o_idx + 1];
        const float ddx = px - tx, ddy = py - ty;

        float val = en * (1.0f / (PRE_LEN * BATCH))
                  + (ddx * ddx + ddy * ddy) * (1.0f / (PRE_LEN * BATCH * 2));

        #pragma unroll
        for (int off = 32; off > 0; off >>= 1)
            val += __shfl_down(val, off, 64);

        if (t == 0)
            ws[b] = val;          // plain store, one per block
    }
}

// Stage 2: single 256-thread block reduces the 1024 partials -> out[0].
__global__ __launch_bounds__(256) void reduce_kernel(
    const float* __restrict__ ws,   // [BATCH]
    float* __restrict__ out)        // [1]
{
    __shared__ float s_part[4];
    const int tid = threadIdx.x;
    const int t   = tid & 63;
    const int q   = tid >> 6;

    // 1024 = 256 threads x 4
    float val = ws[tid] + ws[tid + 256] + ws[tid + 512] + ws[tid + 768];

    #pragma unroll
    for (int off = 32; off > 0; off >>= 1)
        val += __shfl_down(val, off, 64);

    if (t == 0) s_part[q] = val;
    __syncthreads();

    if (tid == 0)
        out[0] = s_part[0] + s_part[1] + s_part[2] + s_part[3];
}

extern "C" void kernel_launch(void* const* d_in, const int* in_sizes, int n_in,
                              void* d_out, int out_size, void* d_ws, size_t ws_size,
                              hipStream_t stream) {
    const float* output = (const float*)d_in[0];
    const float* target = (const float*)d_in[1];
    const float* nbr    = (const float*)d_in[2];
    float* out = (float*)d_out;
    float* ws  = (float*)d_ws;      // >= 1024 floats

    field_loss_kernel<<<dim3(BATCH), dim3(512), 0, stream>>>(output, target, nbr, ws);
    reduce_kernel<<<dim3(1), dim3(256), 0, stream>>>(ws, out);
}